// Round 2
// baseline (20.169 us; speedup 1.0000x reference)
//
#include <hip/hip_runtime.h>

// SymPBC feature kernel for MI355X (v2).
// Math (M=2 dual-pol collapses _triple's pol-swap into a sum over q):
//   B1 = sum_q E[w-n,q]*conj(E[w-m-n,q]);  B2 = sum_q E[w+n,q]*conj(E[w+m+n,q])
//   T1[p] = B1*E[w-m,p] + B2*E[w+m,p]
//   B3 = sum_q E[w-m,q]*conj(E[w-m-n,q]);  B4 = sum_q E[w+m,q]*conj(E[w+m+n,q])
//   T2[p] = B3*E[w-n,p] + B4*E[w+n,p]
//   F = w1*T1 + w2*T2;  w1 = 0.5 iff (m==0 && n==0);  w2 = (n > |m|)
// Output: out[b][w][p][s][c] float32, c={re,im}.

constexpr int W = 16384;
constexpr int WMASK = W - 1;
constexpr int NB = 2;
constexpr int S = 118;
constexpr int HALO = 26;                 // max |m+n|
constexpr int TILE_W = 16;
constexpr int LDSW = TILE_W + 2 * HALO;  // 68

struct C2 { float re, im; };

// s -> (m,n), Python iteration order. Group starts:
// m=-5:0  -4:1  -3:4  -2:10  -1:21  0:46  1:72  2:97  3:108  4:114  5:117
__device__ inline void decode_s(int s, int& m, int& n) {
    const int g = (s>=1)+(s>=4)+(s>=10)+(s>=21)+(s>=46)
                + (s>=72)+(s>=97)+(s>=108)+(s>=114)+(s>=117);
    const int start = (s>=117)?117:(s>=114)?114:(s>=108)?108:(s>=97)?97:
                      (s>=72)?72:(s>=46)?46:(s>=21)?21:(s>=10)?10:
                      (s>=4)?4:(s>=1)?1:0;
    m = g - 5;
    const int am = (m < 0) ? -m : m;
    n = am + (s - start);
}

// bracket(Xa, Xb) = sum_q Xa_q * conj(Xb_q); X = (re0, im0, re1, im1)
__device__ inline C2 bracket(const float4 a, const float4 b) {
    C2 r;
    r.re = a.x*b.x + a.y*b.y + a.z*b.z + a.w*b.w;
    r.im = a.y*b.x - a.x*b.y + a.w*b.z - a.z*b.w;
    return r;
}

__device__ inline float4 compute_f(const float4 Am, const float4 Ap,
                                   const float4 An, const float4 Bn,
                                   const float4 Amn, const float4 Bmn,
                                   const float w1, const float w2) {
    const C2 B1 = bracket(An, Amn);
    const C2 B2 = bracket(Bn, Bmn);
    float r0 = B1.re*Am.x - B1.im*Am.y + B2.re*Ap.x - B2.im*Ap.y;
    float i0 = B1.re*Am.y + B1.im*Am.x + B2.re*Ap.y + B2.im*Ap.x;
    float r1 = B1.re*Am.z - B1.im*Am.w + B2.re*Ap.z - B2.im*Ap.w;
    float i1 = B1.re*Am.w + B1.im*Am.z + B2.re*Ap.w + B2.im*Ap.z;
    r0 *= w1; i0 *= w1; r1 *= w1; i1 *= w1;
    C2 B3 = bracket(Am, Amn);
    C2 B4 = bracket(Ap, Bmn);
    B3.re *= w2; B3.im *= w2; B4.re *= w2; B4.im *= w2;
    r0 += B3.re*An.x - B3.im*An.y + B4.re*Bn.x - B4.im*Bn.y;
    i0 += B3.re*An.y + B3.im*An.x + B4.re*Bn.y + B4.im*Bn.x;
    r1 += B3.re*An.z - B3.im*An.w + B4.re*Bn.z - B4.im*Bn.w;
    i1 += B3.re*An.w + B3.im*An.z + B4.re*Bn.w + B4.im*Bn.z;
    return make_float4(r0, i0, r1, i1);
}

__global__ __launch_bounds__(256) void sympbc_kernel(
    const float* __restrict__ Er, const float* __restrict__ Ei,
    float* __restrict__ out)
{
    __shared__ float4 lds[LDSW];

    const int tid = threadIdx.x;
    const int b = blockIdx.y;
    const int tile0 = blockIdx.x * TILE_W;

    if (tid < LDSW) {
        const int gw = (tile0 - HALO + tid) & WMASK;
        const size_t gi = ((size_t)b * W + gw) * 2;
        const float2 r = *reinterpret_cast<const float2*>(Er + gi);
        const float2 i = *reinterpret_cast<const float2*>(Ei + gi);
        lds[tid] = make_float4(r.x, i.x, r.y, i.y);
    }
    __syncthreads();

    const int sp = tid & 63;        // s-pair index
    const int wsub = tid >> 6;      // 0..3
    if (sp >= 59) return;           // after the barrier: safe

    const int s0 = 2 * sp;
    int m0, n0, m1, n1;
    decode_s(s0, m0, n0);
    decode_s(s0 + 1, m1, n1);
    const int am0 = (m0 < 0) ? -m0 : m0;
    const int am1 = (m1 < 0) ? -m1 : m1;
    const float w1a = (s0 == 46) ? 0.5f : 1.0f;   // (m,n)==(0,0) is s=46
    const float w2a = (n0 > am0) ? 1.0f : 0.0f;
    const float w2b = (n1 > am1) ? 1.0f : 0.0f;   // s1 odd -> never (0,0)
    const bool mdiff = (m1 != m0);                // 4 lanes only

    // out flat: (((b*W + w)*2 + p)*S + s)*2 + c
    float* obase = out + ((size_t)b * W + tile0) * (2 * S * 2) + (size_t)s0 * 2;

    #pragma unroll
    for (int it = 0; it < TILE_W / 4; ++it) {
        const int wl = wsub + 4 * it;
        const int ci = HALO + wl;

        const float4 Am = lds[ci - m0];
        const float4 Ap = lds[ci + m0];
        float4 Am1v = Am, Ap1v = Ap;
        if (mdiff) { Am1v = lds[ci - m1]; Ap1v = lds[ci + m1]; }

        const float4 An0  = lds[ci - n0];
        const float4 Bn0  = lds[ci + n0];
        const float4 Amn0 = lds[ci - m0 - n0];
        const float4 Bmn0 = lds[ci + m0 + n0];
        const float4 An1  = lds[ci - n1];
        const float4 Bn1  = lds[ci + n1];
        const float4 Amn1 = lds[ci - m1 - n1];
        const float4 Bmn1 = lds[ci + m1 + n1];

        const float4 F0 = compute_f(Am,   Ap,   An0, Bn0, Amn0, Bmn0, w1a, w2a);
        const float4 F1 = compute_f(Am1v, Ap1v, An1, Bn1, Amn1, Bmn1, 1.0f, w2b);

        float* orow = obase + (size_t)wl * (2 * S * 2);
        *reinterpret_cast<float4*>(orow) =
            make_float4(F0.x, F0.y, F1.x, F1.y);                 // p=0
        *reinterpret_cast<float4*>(orow + S * 2) =
            make_float4(F0.z, F0.w, F1.z, F1.w);                 // p=1
    }
}

extern "C" void kernel_launch(void* const* d_in, const int* in_sizes, int n_in,
                              void* d_out, int out_size, void* d_ws, size_t ws_size,
                              hipStream_t stream) {
    const float* Er = (const float*)d_in[0];
    const float* Ei = (const float*)d_in[1];
    float* out = (float*)d_out;
    dim3 grid(W / TILE_W, NB);
    sympbc_kernel<<<grid, dim3(256), 0, stream>>>(Er, Ei, out);
}